// Round 10
// baseline (82.855 us; speedup 1.0000x reference)
//
#include <hip/hip_runtime.h>

typedef __attribute__((ext_vector_type(8))) short short8;
typedef __attribute__((ext_vector_type(4))) float f32x4;

#define HF 256
#define WF 256

typedef const __attribute__((address_space(1))) void gbl_void;
typedef __attribute__((address_space(3))) void lds_void;

__device__ __forceinline__ ushort f2bf(float f) {
    uint u = __builtin_bit_cast(uint, f);
    u = (u + 0x7FFFu + ((u >> 16) & 1u)) >> 16;
    return (ushort)u;
}
__device__ __forceinline__ uint pack2(float a, float b) {
    return (uint)f2bf(a) | ((uint)f2bf(b) << 16);
}
__device__ __forceinline__ float prelu(float v, float al) { return v >= 0.f ? v : al * v; }

// ---------------------------------------------------------------------------
// Weight prep A: w[o][c][3][3] f32 -> wT[tap][o][c] bf16; also zeroes zeroBuf.
// ---------------------------------------------------------------------------
__global__ __launch_bounds__(256) void k_wprep(const float* __restrict__ w1,
                                               const float* __restrict__ w2,
                                               ushort* __restrict__ wT1,
                                               ushort* __restrict__ wT2,
                                               uint4* __restrict__ zeroBuf) {
    if (blockIdx.x == 0 && threadIdx.x < 16)
        zeroBuf[threadIdx.x] = make_uint4(0u, 0u, 0u, 0u);
    int idx = blockIdx.x * 256 + threadIdx.x;   // [tap][o][c] : 9*64*64 = 36864
    int tap = idx >> 12;
    int oc  = idx & 4095;
    int src = oc * 9 + tap;
    wT1[idx] = f2bf(w1[src]);
    wT2[idx] = f2bf(w2[src]);
}

// ---------------------------------------------------------------------------
// Weight prep B: wup[c][o][p][q] f32 -> wupT[out = (p*2+q)*64 + o][c] bf16
// ---------------------------------------------------------------------------
__global__ __launch_bounds__(256) void k_wprep_up(const float* __restrict__ wup,
                                                  ushort* __restrict__ wupT) {
    int idx = blockIdx.x * 256 + threadIdx.x;   // 256*128 = 32768
    int out = idx >> 7;
    int c   = idx & 127;
    int k   = out >> 6;       // p*2+q
    int o   = out & 63;
    wupT[idx] = f2bf(wup[c * 256 + o * 4 + k]);
}

// ---------------------------------------------------------------------------
// ConvTranspose2d k=2 s=2 for b=2,3 via bf16 MFMA -> upB NHWC [z][y][x][64]
// (unchanged — known good)
// ---------------------------------------------------------------------------
__global__ __launch_bounds__(512) void k_upsample_mfma(const float* __restrict__ x1,
                                                       const ushort* __restrict__ wupT,
                                                       const float* __restrict__ bup,
                                                       ushort* __restrict__ upB) {
    __shared__ __align__(16) char lds[81920];

    const int t   = threadIdx.x;
    const int l   = t & 63;
    const int l15 = l & 15;
    const int l4  = l >> 4;
    const int w   = t >> 6;
    const int pg  = w & 3;
    const int oh  = w >> 2;
    const int i   = blockIdx.x >> 1;
    const int j0  = (blockIdx.x & 1) * 64;
    const int z   = blockIdx.y;
    const int gb  = 2 + z;

    {
        const int j  = t & 63;
        const int cg = t >> 6;
        const size_t base = ((size_t)gb * 128) * 16384 + (size_t)i * 128 + j0 + j;
        float xv[16];
#pragma unroll
        for (int r = 0; r < 2; ++r)
#pragma unroll
            for (int cc = 0; cc < 8; ++cc)
                xv[r * 8 + cc] = x1[base + (size_t)(cg * 16 + r * 8 + cc) * 16384];
#pragma unroll
        for (int r = 0; r < 2; ++r) {
            short8 pk;
#pragma unroll
            for (int cc = 0; cc < 8; ++cc) pk[cc] = (short)f2bf(xv[r * 8 + cc]);
            int ad = (j * 256 + (cg * 16 + r * 8) * 2) ^ ((j & 15) << 4);
            *(short8*)(lds + ad) = pk;
        }
    }
    {
        const uint4* src = (const uint4*)wupT;
#pragma unroll
        for (int rep = 0; rep < 8; ++rep) {
            int q   = rep * 512 + t;
            int out = q >> 4, c16 = q & 15;
            int ad  = 16384 + ((out * 256 + c16 * 16) ^ ((out & 15) << 4));
            *(uint4*)(lds + ad) = src[q];
        }
    }
    float bvv[4];
#pragma unroll
    for (int ob = 0; ob < 4; ++ob) bvv[ob] = bup[ob * 16 + l15];
    __syncthreads();

    f32x4 acc[2][4];
#pragma unroll
    for (int kk = 0; kk < 2; ++kk)
#pragma unroll
        for (int ob = 0; ob < 4; ++ob) acc[kk][ob] = (f32x4){0.f, 0.f, 0.f, 0.f};

#pragma unroll
    for (int ks = 0; ks < 4; ++ks) {
        const int cb = ks * 64 + (l4 << 4);
        const int rowA = pg * 16 + l15;
        short8 xfr = *(const short8*)(lds + ((rowA * 256 + cb) ^ ((rowA & 15) << 4)));
#pragma unroll
        for (int kk = 0; kk < 2; ++kk)
#pragma unroll
            for (int ob = 0; ob < 4; ++ob) {
                int out = (oh * 2 + kk) * 64 + ob * 16 + l15;
                short8 wfr = *(const short8*)(lds + 16384 +
                              ((out * 256 + cb) ^ ((out & 15) << 4)));
                acc[kk][ob] = __builtin_amdgcn_mfma_f32_16x16x32_bf16(xfr, wfr, acc[kk][ob], 0, 0, 0);
            }
    }
    __syncthreads();

    ushort* OUT = (ushort*)lds;
#pragma unroll
    for (int kk = 0; kk < 2; ++kk) {
        const int k = oh * 2 + kk, p = k >> 1, q = k & 1;
#pragma unroll
        for (int ob = 0; ob < 4; ++ob) {
            const int o = ob * 16 + l15;
#pragma unroll
            for (int r = 0; r < 4; ++r) {
                int jl = pg * 16 + l4 * 4 + r;
                int x  = 2 * jl + q;
                OUT[(p * 128 + x) * 64 + o] = f2bf(acc[kk][ob][r] + bvv[ob]);
            }
        }
    }
    __syncthreads();

#pragma unroll
    for (int rep = 0; rep < 4; ++rep) {
        int idx = rep * 512 + t;
        int p   = idx >> 10;
        int y   = 2 * i + p;
        uint4 v = *(const uint4*)(lds + idx * 16);
        size_t g = (size_t)(z * HF + y) * 2048 + (size_t)j0 * 16 + (idx & 1023);
        ((uint4*)upB)[g] = v;
    }
}

// ---------------------------------------------------------------------------
// k_conv v7: persistent 4-tile block. Grid 256 (1/CU). Block owns a 32x32
// output strip = 4 tiles of 32x8. Weights (72 KB) staged ONCE; input tiles
// double-buffered (2 x 2752 uint4 = 86 KB): stage(t+1) issued async before
// compute(t), barrier after compute drains it under cover of MFMA work.
// Wave = 1 output row x 64 couts, acc[2][4]. LDS total 158 KB.
// ---------------------------------------------------------------------------
template<int IN_SPLIT, int OUT_NHWC>
__global__ __launch_bounds__(512, 1) void k_conv(const float* __restrict__ x2,
                                                 const ushort* __restrict__ upB,
                                                 const ushort* __restrict__ inB,
                                                 const ushort* __restrict__ wT,
                                                 const float* __restrict__ bias,
                                                 const float* __restrict__ alpha,
                                                 const uint4* __restrict__ zeroBuf,
                                                 ushort* __restrict__ outB,
                                                 float* __restrict__ outF) {
    __shared__ __align__(16) ushort inLA[2752 * 8];      // 43 KB + pad
    __shared__ __align__(16) ushort inLB[2752 * 8];
    __shared__ __align__(16) ushort wL[9 * 64 * 64];     // 72 KB [tap][o][c], swz on o

    const int t   = threadIdx.x;
    const int wv  = t >> 6;          // wave id -> output row within tile (0..7)
    const int l   = t & 63;
    const int l15 = l & 15;
    const int l4  = l >> 4;
    const int x0  = (blockIdx.x & 7) * 32;
    const int y0  = (blockIdx.x >> 3) * 32;
    const int b   = blockIdx.y;

    const bool manual = (IN_SPLIT == 1) && (b < 2);      // conv1 batches 0,1: x2 f32
    const ushort* src = (IN_SPLIT == 1) ? upB : inB;
    const int bb = (IN_SPLIT == 1) ? (b - 2) : b;

    // ---- stage ALL weights once: linear dest, pre-swizzled source (async)
    {
        const char* wTb = (const char*)wT;
#pragma unroll
        for (int rep = 0; rep < 9; ++rep) {
            int d   = rep * 512 + t;
            int tap = d >> 9;
            int dp  = d & 511;
            int s   = (tap << 9) + (dp ^ ((dp >> 3) & 7));
            __builtin_amdgcn_global_load_lds(
                (gbl_void*)(wTb + (size_t)s * 16),
                (lds_void*)((char*)wL + (size_t)((rep << 9) + (wv << 6)) * 16),
                16, 0, 0);
        }
    }

    // ---- tile staging helpers -------------------------------------------
    // async (bf16 NHWC source): 10x34x64ch = 2720 uint4, padded to 2752
    auto stage_async = [&](char* dst, int y0t) {
#pragma unroll
        for (int rep = 0; rep < 6; ++rep) {
            int d = rep * 512 + t;
            if (d >= 2752) break;                  // rep5: waves 3..7 skip (uniform)
            int r  = d / 272;
            int wi = d - r * 272;
            int wq = wi ^ ((wi >> 3) & 7);         // pre-swizzled source element
            int x  = wq >> 3, c8 = wq & 7;
            int gy = y0t - 1 + r;
            int gx = x0 - 1 + x;
            const void* g;
            if (d < 2720 && (unsigned)gy < HF && (unsigned)gx < WF) {
                size_t pos = (size_t)(bb * HF + gy) * WF + gx;
                g = (const void*)(src + pos * 64 + c8 * 8);
            } else {
                g = (const void*)zeroBuf;
            }
            __builtin_amdgcn_global_load_lds(
                (gbl_void*)g,
                (lds_void*)(dst + (size_t)((rep << 9) + (wv << 6)) * 16),
                16, 0, 0);
        }
    };
    // manual (x2 f32 NHWC -> bf16), same LDS layout
    auto stage_manual = [&](char* dst, int y0t) {
        for (int q = t; q < 2720; q += 512) {
            int r   = q / 272;
            int rem = q - r * 272;
            int x   = rem >> 3;
            int c8  = rem & 7;
            int gy = y0t - 1 + r;
            int gx = x0 - 1 + x;
            uint4 v = make_uint4(0u, 0u, 0u, 0u);
            if ((unsigned)gy < HF && (unsigned)gx < WF) {
                size_t pos = (size_t)(b * HF + gy) * WF + gx;
                const float4* s = (const float4*)(x2 + pos * 64 + c8 * 8);
                float4 u0 = s[0], u1 = s[1];
                v = make_uint4(pack2(u0.x, u0.y), pack2(u0.z, u0.w),
                               pack2(u1.x, u1.y), pack2(u1.z, u1.w));
            }
            int ad = (q * 16) ^ ((x & 7) << 4);
            *(uint4*)(dst + ad) = v;
        }
    };

    // ---- prologue: stage tile 0
    if (manual) stage_manual((char*)inLA, y0);
    else        stage_async((char*)inLA, y0);
    __syncthreads();

    const float al = alpha[0];
    float4 bv4[4];
    float  bsc[4];
#pragma unroll
    for (int nf = 0; nf < 4; ++nf) {
        bv4[nf] = *(const float4*)(bias + nf * 16 + (l4 << 2));
        bsc[nf] = bias[nf * 16 + l15];
    }

    // ---- 4-tile loop: prefetch next, compute current, barrier
#pragma unroll 1
    for (int tt = 0; tt < 4; ++tt) {
        char* cur = (tt & 1) ? (char*)inLB : (char*)inLA;
        char* nxt = (tt & 1) ? (char*)inLA : (char*)inLB;
        const int y0t = y0 + tt * 8;

        if (tt < 3) {
            if (manual) stage_manual(nxt, y0t + 8);
            else        stage_async(nxt, y0t + 8);
        }

        f32x4 acc[2][4];
#pragma unroll
        for (int m = 0; m < 2; ++m)
#pragma unroll
            for (int nf = 0; nf < 4; ++nf) acc[m][nf] = (f32x4){0.f, 0.f, 0.f, 0.f};

#pragma unroll 1
        for (int tap = 0; tap < 9; ++tap) {
            const int ky = tap / 3;
            const int kx = tap - ky * 3;
            const char* wPage = (const char*)wL + tap * 8192;
#pragma unroll
            for (int ks = 0; ks < 2; ++ks) {
                short8 wfr[4];
#pragma unroll
                for (int nf = 0; nf < 4; ++nf) {
                    int o = nf * 16 + l15;
                    int ad = (o * 128 + ks * 64 + (l4 << 4)) ^ ((o & 7) << 4);
                    wfr[nf] = *(const short8*)(wPage + ad);
                }
#pragma unroll
                for (int m = 0; m < 2; ++m) {
                    int ry = wv + ky;
                    int xl = m * 16 + l15 + kx;
                    int ad = ((ry * 34 + xl) * 128 + ks * 64 + (l4 << 4)) ^ ((xl & 7) << 4);
                    short8 ifr = *(const short8*)(cur + ad);
#pragma unroll
                    for (int nf = 0; nf < 4; ++nf) {
                        if (OUT_NHWC)
                            acc[m][nf] = __builtin_amdgcn_mfma_f32_16x16x32_bf16(
                                wfr[nf], ifr, acc[m][nf], 0, 0, 0);   // row=cout, col=pos
                        else
                            acc[m][nf] = __builtin_amdgcn_mfma_f32_16x16x32_bf16(
                                ifr, wfr[nf], acc[m][nf], 0, 0, 0);   // row=pos, col=cout
                    }
                }
            }
        }

        // ---- epilogue for this tile
        const int y = y0t + wv;
        if (OUT_NHWC) {
#pragma unroll
            for (int m = 0; m < 2; ++m) {
                int x = x0 + m * 16 + l15;
#pragma unroll
                for (int nf = 0; nf < 4; ++nf) {
                    f32x4 v = acc[m][nf];
                    uint lo = pack2(prelu(v.x + bv4[nf].x, al), prelu(v.y + bv4[nf].y, al));
                    uint hi = pack2(prelu(v.z + bv4[nf].z, al), prelu(v.w + bv4[nf].w, al));
                    int cb = nf * 16 + (l4 << 2);
                    *(uint2*)(outB + ((size_t)(b * HF + y) * WF + x) * 64 + cb) =
                        make_uint2(lo, hi);
                }
            }
        } else {
#pragma unroll
            for (int m = 0; m < 2; ++m) {
                int xb = x0 + m * 16 + (l4 << 2);
#pragma unroll
                for (int nf = 0; nf < 4; ++nf) {
                    f32x4 v = acc[m][nf];
                    int cout = nf * 16 + l15;
                    float4 st;
                    st.x = prelu(v.x + bsc[nf], al);
                    st.y = prelu(v.y + bsc[nf], al);
                    st.z = prelu(v.z + bsc[nf], al);
                    st.w = prelu(v.w + bsc[nf], al);
                    *(float4*)(outF + (((size_t)b * 64 + cout) << 16) + y * WF + xb) = st;
                }
            }
        }
        __syncthreads();   // drains prefetch (covered by compute) + swaps buffers
    }
}

// ---------------------------------------------------------------------------
extern "C" void kernel_launch(void* const* d_in, const int* in_sizes, int n_in,
                              void* d_out, int out_size, void* d_ws, size_t ws_size,
                              hipStream_t stream) {
    const float* x1  = (const float*)d_in[0];
    const float* x2  = (const float*)d_in[1];
    const float* wup = (const float*)d_in[2];
    const float* bup = (const float*)d_in[3];
    const float* w1  = (const float*)d_in[4];
    const float* b1  = (const float*)d_in[5];
    const float* a1  = (const float*)d_in[6];
    const float* w2  = (const float*)d_in[7];
    const float* b2  = (const float*)d_in[8];
    const float* a2  = (const float*)d_in[9];

    char* ws = (char*)d_ws;
    ushort* upB  = (ushort*)ws;                          // 16 MiB (b=2,3 NHWC bf16)
    ushort* hB   = (ushort*)(ws + (size_t)(16 << 20));   // 32 MiB (NHWC bf16)
    ushort* wT1  = (ushort*)(ws + (size_t)(48 << 20));   // 72 KiB
    ushort* wT2  = wT1 + 9 * 64 * 64;                    // 72 KiB
    ushort* wupT = wT2 + 9 * 64 * 64;                    // 64 KiB
    uint4*  zeroBuf = (uint4*)(ws + (size_t)(49 << 20)); // 256 B, zeroed by k_wprep
    float* out = (float*)d_out;

    k_wprep<<<144, 256, 0, stream>>>(w1, w2, wT1, wT2, zeroBuf);
    k_wprep_up<<<128, 256, 0, stream>>>(wup, wupT);
    k_upsample_mfma<<<dim3(256, 2), 512, 0, stream>>>(x1, wupT, bup, upB);
    k_conv<1, 1><<<dim3(64, 4), 512, 0, stream>>>(x2, upB, nullptr, wT1, b1, a1, zeroBuf, hB, nullptr);
    k_conv<0, 0><<<dim3(64, 4), 512, 0, stream>>>(nullptr, nullptr, hB, wT2, b2, a2, zeroBuf, nullptr, out);
}

// Round 11
// 80.238 us; speedup vs baseline: 1.0326x; 1.0326x over previous
//
#include <hip/hip_runtime.h>

typedef __attribute__((ext_vector_type(8))) short short8;
typedef __attribute__((ext_vector_type(4))) float f32x4;

#define HF 256
#define WF 256

typedef const __attribute__((address_space(1))) void gbl_void;
typedef __attribute__((address_space(3))) void lds_void;

__device__ __forceinline__ ushort f2bf(float f) {
    uint u = __builtin_bit_cast(uint, f);
    u = (u + 0x7FFFu + ((u >> 16) & 1u)) >> 16;
    return (ushort)u;
}
__device__ __forceinline__ uint pack2(float a, float b) {
    return (uint)f2bf(a) | ((uint)f2bf(b) << 16);
}
__device__ __forceinline__ float prelu(float v, float al) { return v >= 0.f ? v : al * v; }

// ---------------------------------------------------------------------------
// Fused weight prep: conv weights w[o][c][3][3] -> wT[tap][o][c] bf16 (x2),
// up weights wup[c][o][p][q] -> wupT[(p*2+q)*64+o][c] bf16, zeroBuf.
// ---------------------------------------------------------------------------
__global__ __launch_bounds__(256) void k_wprep(const float* __restrict__ w1,
                                               const float* __restrict__ w2,
                                               const float* __restrict__ wup,
                                               ushort* __restrict__ wT1,
                                               ushort* __restrict__ wT2,
                                               ushort* __restrict__ wupT,
                                               uint4* __restrict__ zeroBuf) {
    int idx = blockIdx.x * 256 + threadIdx.x;
    if (blockIdx.x == 0 && threadIdx.x < 16)
        zeroBuf[threadIdx.x] = make_uint4(0u, 0u, 0u, 0u);
    if (idx < 36864) {                 // [tap][o][c] : 9*64*64
        int tap = idx >> 12;
        int oc  = idx & 4095;
        int src = oc * 9 + tap;
        wT1[idx] = f2bf(w1[src]);
        wT2[idx] = f2bf(w2[src]);
    }
    if (idx < 32768) {                 // [out][c] : 256*128
        int out = idx >> 7;
        int c   = idx & 127;
        int k   = out >> 6;            // p*2+q
        int o   = out & 63;
        wupT[idx] = f2bf(wup[c * 256 + o * 4 + k]);
    }
}

// ---------------------------------------------------------------------------
// ConvTranspose2d k=2 s=2 for b=2,3 via bf16 MFMA -> upB NHWC [z][y][x][64]
// (unchanged — known good)
// ---------------------------------------------------------------------------
__global__ __launch_bounds__(512) void k_upsample_mfma(const float* __restrict__ x1,
                                                       const ushort* __restrict__ wupT,
                                                       const float* __restrict__ bup,
                                                       ushort* __restrict__ upB) {
    __shared__ __align__(16) char lds[81920];

    const int t   = threadIdx.x;
    const int l   = t & 63;
    const int l15 = l & 15;
    const int l4  = l >> 4;
    const int w   = t >> 6;
    const int pg  = w & 3;
    const int oh  = w >> 2;
    const int i   = blockIdx.x >> 1;
    const int j0  = (blockIdx.x & 1) * 64;
    const int z   = blockIdx.y;
    const int gb  = 2 + z;

    {
        const int j  = t & 63;
        const int cg = t >> 6;
        const size_t base = ((size_t)gb * 128) * 16384 + (size_t)i * 128 + j0 + j;
        float xv[16];
#pragma unroll
        for (int r = 0; r < 2; ++r)
#pragma unroll
            for (int cc = 0; cc < 8; ++cc)
                xv[r * 8 + cc] = x1[base + (size_t)(cg * 16 + r * 8 + cc) * 16384];
#pragma unroll
        for (int r = 0; r < 2; ++r) {
            short8 pk;
#pragma unroll
            for (int cc = 0; cc < 8; ++cc) pk[cc] = (short)f2bf(xv[r * 8 + cc]);
            int ad = (j * 256 + (cg * 16 + r * 8) * 2) ^ ((j & 15) << 4);
            *(short8*)(lds + ad) = pk;
        }
    }
    {
        const uint4* src = (const uint4*)wupT;
#pragma unroll
        for (int rep = 0; rep < 8; ++rep) {
            int q   = rep * 512 + t;
            int out = q >> 4, c16 = q & 15;
            int ad  = 16384 + ((out * 256 + c16 * 16) ^ ((out & 15) << 4));
            *(uint4*)(lds + ad) = src[q];
        }
    }
    float bvv[4];
#pragma unroll
    for (int ob = 0; ob < 4; ++ob) bvv[ob] = bup[ob * 16 + l15];
    __syncthreads();

    f32x4 acc[2][4];
#pragma unroll
    for (int kk = 0; kk < 2; ++kk)
#pragma unroll
        for (int ob = 0; ob < 4; ++ob) acc[kk][ob] = (f32x4){0.f, 0.f, 0.f, 0.f};

#pragma unroll
    for (int ks = 0; ks < 4; ++ks) {
        const int cb = ks * 64 + (l4 << 4);
        const int rowA = pg * 16 + l15;
        short8 xfr = *(const short8*)(lds + ((rowA * 256 + cb) ^ ((rowA & 15) << 4)));
#pragma unroll
        for (int kk = 0; kk < 2; ++kk)
#pragma unroll
            for (int ob = 0; ob < 4; ++ob) {
                int out = (oh * 2 + kk) * 64 + ob * 16 + l15;
                short8 wfr = *(const short8*)(lds + 16384 +
                              ((out * 256 + cb) ^ ((out & 15) << 4)));
                acc[kk][ob] = __builtin_amdgcn_mfma_f32_16x16x32_bf16(xfr, wfr, acc[kk][ob], 0, 0, 0);
            }
    }
    __syncthreads();

    ushort* OUT = (ushort*)lds;
#pragma unroll
    for (int kk = 0; kk < 2; ++kk) {
        const int k = oh * 2 + kk, p = k >> 1, q = k & 1;
#pragma unroll
        for (int ob = 0; ob < 4; ++ob) {
            const int o = ob * 16 + l15;
#pragma unroll
            for (int r = 0; r < 4; ++r) {
                int jl = pg * 16 + l4 * 4 + r;
                int x  = 2 * jl + q;
                OUT[(p * 128 + x) * 64 + o] = f2bf(acc[kk][ob][r] + bvv[ob]);
            }
        }
    }
    __syncthreads();

#pragma unroll
    for (int rep = 0; rep < 4; ++rep) {
        int idx = rep * 512 + t;
        int p   = idx >> 10;
        int y   = 2 * i + p;
        uint4 v = *(const uint4*)(lds + idx * 16);
        size_t g = (size_t)(z * HF + y) * 2048 + (size_t)j0 * 16 + (idx & 1023);
        ((uint4*)upB)[g] = v;
    }
}

// ---------------------------------------------------------------------------
// k_conv v8: SAME tile/LDS/swizzle/staging as R9 (proven) but 1024 threads =
// 16 waves -> 4 waves/SIMD (TLP experiment). Wave = 1 y-row x 32 x x 64 couts,
// acc[2][4] = 32 VGPR. VGPR must stay <=128 for 16 waves/CU.
// ---------------------------------------------------------------------------
template<int IN_MODE, int OUT_NHWC>
__global__ __launch_bounds__(1024, 1) void k_conv(const float* __restrict__ x2,
                                                  const ushort* __restrict__ upB,
                                                  const ushort* __restrict__ inB,
                                                  const ushort* __restrict__ wT,
                                                  const float* __restrict__ bias,
                                                  const float* __restrict__ alpha,
                                                  const uint4* __restrict__ zeroBuf,
                                                  ushort* __restrict__ outB,
                                                  float* __restrict__ outF) {
    __shared__ __align__(16) ushort inL[5120 * 8];       // 80 KB (4896 used + pad)
    __shared__ __align__(16) ushort wL[9 * 64 * 64];     // 72 KB [tap][o][c], swz on o

    const int t   = threadIdx.x;
    const int wv  = t >> 6;          // wave id -> output row (0..15)
    const int l   = t & 63;
    const int l15 = l & 15;
    const int l4  = l >> 4;
    const int x0  = (blockIdx.x & 7) * 32;
    const int y0  = (blockIdx.x >> 3) * 16;
    const int b   = blockIdx.y;

    // ---- stage ALL weights: linear dest, pre-swizzled source (4608 uint4)
    {
        const char* wTb = (const char*)wT;
#pragma unroll
        for (int rep = 0; rep < 4; ++rep) {
            int d   = rep * 1024 + t;
            int tap = d >> 9;
            int dp  = d & 511;
            int s   = (tap << 9) + (dp ^ ((dp >> 3) & 7));
            __builtin_amdgcn_global_load_lds(
                (gbl_void*)(wTb + (size_t)s * 16),
                (lds_void*)((char*)wL + (size_t)((rep << 10) + (wv << 6)) * 16),
                16, 0, 0);
        }
        if (wv < 8) {                              // wave-uniform tail: 4096..4607
            int d   = 4096 + (wv << 6) + l;
            int tap = d >> 9;
            int dp  = d & 511;
            int s   = (tap << 9) + (dp ^ ((dp >> 3) & 7));
            __builtin_amdgcn_global_load_lds(
                (gbl_void*)(wTb + (size_t)s * 16),
                (lds_void*)((char*)wL + (size_t)(4096 + (wv << 6)) * 16),
                16, 0, 0);
        }
    }

    // ---- stage input tile (18 x 34 x 64ch = 4896 uint4, padded to 5120)
    if (IN_MODE == 1 || b >= 2) {
        const ushort* src0 = (IN_MODE == 1) ? inB : upB;
        const int bb = (IN_MODE == 1) ? b : (b - 2);
#pragma unroll
        for (int rep = 0; rep < 5; ++rep) {
            int d  = rep * 1024 + t;                 // 0..5119
            int r  = d / 272;
            int wi = d - r * 272;
            int wq = wi ^ ((wi >> 3) & 7);           // pre-swizzled source element
            int x  = wq >> 3, c8 = wq & 7;
            int gy = y0 - 1 + r;
            int gx = x0 - 1 + x;
            const void* g;
            if (d < 4896 && (unsigned)gy < HF && (unsigned)gx < WF) {
                size_t pos = (size_t)(bb * HF + gy) * WF + gx;
                g = (const void*)(src0 + pos * 64 + c8 * 8);
            } else {
                g = (const void*)zeroBuf;
            }
            __builtin_amdgcn_global_load_lds(
                (gbl_void*)g,
                (lds_void*)((char*)inL + (size_t)((rep << 10) + (wv << 6)) * 16),
                16, 0, 0);
        }
    } else {
        // manual path: x2 f32 NHWC -> bf16, swizzled ds_write
        for (int q = t; q < 18 * 34 * 8; q += 1024) {
            int r   = q / 272;
            int rem = q - r * 272;
            int x   = rem >> 3;
            int c8  = rem & 7;
            int gy = y0 - 1 + r;
            int gx = x0 - 1 + x;
            uint4 v = make_uint4(0u, 0u, 0u, 0u);
            if ((unsigned)gy < HF && (unsigned)gx < WF) {
                size_t pos = (size_t)(b * HF + gy) * WF + gx;
                const float4* s = (const float4*)(x2 + pos * 64 + c8 * 8);
                float4 u0 = s[0], u1 = s[1];
                v = make_uint4(pack2(u0.x, u0.y), pack2(u0.z, u0.w),
                               pack2(u1.x, u1.y), pack2(u1.z, u1.w));
            }
            int ad = (q * 16) ^ ((x & 7) << 4);
            *(uint4*)((char*)inL + ad) = v;
        }
    }
    __syncthreads();

    f32x4 acc[2][4];   // [m][nf]
#pragma unroll
    for (int m = 0; m < 2; ++m)
#pragma unroll
        for (int nf = 0; nf < 4; ++nf) acc[m][nf] = (f32x4){0.f, 0.f, 0.f, 0.f};

    // ---- K-loop: 9 taps, pure LDS + MFMA, zero barriers
#pragma unroll 1
    for (int tap = 0; tap < 9; ++tap) {
        const int ky = tap / 3;
        const int kx = tap - ky * 3;
        const char* wPage = (const char*)wL + tap * 8192;
#pragma unroll
        for (int ks = 0; ks < 2; ++ks) {
            short8 wfr[4];
#pragma unroll
            for (int nf = 0; nf < 4; ++nf) {
                int o = nf * 16 + l15;
                int ad = (o * 128 + ks * 64 + (l4 << 4)) ^ ((o & 7) << 4);
                wfr[nf] = *(const short8*)(wPage + ad);
            }
#pragma unroll
            for (int m = 0; m < 2; ++m) {
                int ry = wv + ky;
                int xl = m * 16 + l15 + kx;
                int ad = ((ry * 34 + xl) * 128 + ks * 64 + (l4 << 4)) ^ ((xl & 7) << 4);
                short8 ifr = *(const short8*)((const char*)inL + ad);
#pragma unroll
                for (int nf = 0; nf < 4; ++nf) {
                    if (OUT_NHWC)
                        acc[m][nf] = __builtin_amdgcn_mfma_f32_16x16x32_bf16(
                            wfr[nf], ifr, acc[m][nf], 0, 0, 0);   // row=cout, col=pos
                    else
                        acc[m][nf] = __builtin_amdgcn_mfma_f32_16x16x32_bf16(
                            ifr, wfr[nf], acc[m][nf], 0, 0, 0);   // row=pos, col=cout
                }
            }
        }
    }

    const float al = alpha[0];
    const int y = y0 + wv;
    if (OUT_NHWC) {
        float4 bv[4];
#pragma unroll
        for (int nf = 0; nf < 4; ++nf) bv[nf] = *(const float4*)(bias + nf * 16 + (l4 << 2));
#pragma unroll
        for (int m = 0; m < 2; ++m) {
            int x = x0 + m * 16 + l15;
#pragma unroll
            for (int nf = 0; nf < 4; ++nf) {
                f32x4 v = acc[m][nf];
                uint lo = pack2(prelu(v.x + bv[nf].x, al), prelu(v.y + bv[nf].y, al));
                uint hi = pack2(prelu(v.z + bv[nf].z, al), prelu(v.w + bv[nf].w, al));
                int cb = nf * 16 + (l4 << 2);
                *(uint2*)(outB + ((size_t)(b * HF + y) * WF + x) * 64 + cb) = make_uint2(lo, hi);
            }
        }
    } else {
        float bb[4];
#pragma unroll
        for (int nf = 0; nf < 4; ++nf) bb[nf] = bias[nf * 16 + l15];
#pragma unroll
        for (int m = 0; m < 2; ++m) {
            int xb = x0 + m * 16 + (l4 << 2);
#pragma unroll
            for (int nf = 0; nf < 4; ++nf) {
                f32x4 v = acc[m][nf];
                int cout = nf * 16 + l15;
                float4 st;
                st.x = prelu(v.x + bb[nf], al);
                st.y = prelu(v.y + bb[nf], al);
                st.z = prelu(v.z + bb[nf], al);
                st.w = prelu(v.w + bb[nf], al);
                *(float4*)(outF + (((size_t)b * 64 + cout) << 16) + y * WF + xb) = st;
            }
        }
    }
}

// ---------------------------------------------------------------------------
extern "C" void kernel_launch(void* const* d_in, const int* in_sizes, int n_in,
                              void* d_out, int out_size, void* d_ws, size_t ws_size,
                              hipStream_t stream) {
    const float* x1  = (const float*)d_in[0];
    const float* x2  = (const float*)d_in[1];
    const float* wup = (const float*)d_in[2];
    const float* bup = (const float*)d_in[3];
    const float* w1  = (const float*)d_in[4];
    const float* b1  = (const float*)d_in[5];
    const float* a1  = (const float*)d_in[6];
    const float* w2  = (const float*)d_in[7];
    const float* b2  = (const float*)d_in[8];
    const float* a2  = (const float*)d_in[9];

    char* ws = (char*)d_ws;
    ushort* upB  = (ushort*)ws;                          // 16 MiB (b=2,3 NHWC bf16)
    ushort* hB   = (ushort*)(ws + (size_t)(16 << 20));   // 32 MiB (NHWC bf16)
    ushort* wT1  = (ushort*)(ws + (size_t)(48 << 20));   // 72 KiB
    ushort* wT2  = wT1 + 9 * 64 * 64;                    // 72 KiB
    ushort* wupT = wT2 + 9 * 64 * 64;                    // 64 KiB
    uint4*  zeroBuf = (uint4*)(ws + (size_t)(49 << 20)); // 256 B, zeroed by k_wprep
    float* out = (float*)d_out;

    k_wprep<<<144, 256, 0, stream>>>(w1, w2, wup, wT1, wT2, wupT, zeroBuf);
    k_upsample_mfma<<<dim3(256, 2), 512, 0, stream>>>(x1, wupT, bup, upB);
    k_conv<0, 1><<<dim3(128, 4), 1024, 0, stream>>>(x2, upB, nullptr, wT1, b1, a1, zeroBuf, hB, nullptr);
    k_conv<1, 0><<<dim3(128, 4), 1024, 0, stream>>>(nullptr, nullptr, hB, wT2, b2, a2, zeroBuf, nullptr, out);
}